// Round 8
// baseline (89.887 us; speedup 1.0000x reference)
//
#include <hip/hip_runtime.h>

static constexpr int N = 128;
static constexpr int F = 128;
static constexpr int H = 8;
static constexpr int NATTR = 3;
static constexpr int M = N * N;        // 16384
static constexpr int OUTW = 320;       // F + 8*16 + 8*8
static constexpr int MSL = 64;         // m-splits in edge attention
static constexpr int CH = M / MSL;     // 256
static constexpr int HG = 2;           // heads per ea block
static constexpr float LOG2E = 1.4426950408889634f;

__device__ __forceinline__ float leaky(float x) { return fmaxf(x, 0.2f * x); }
// LDS bank-conflict swizzles (bijective within the plane; same map on write+read)
__device__ __forceinline__ int swz4(int s) { return s ^ ((s >> 3) & 7); }   // float4 slots
__device__ __forceinline__ int swz2(int s) { return s ^ ((s >> 4) & 3); }   // float2 slots

// ---------------------------------------------------------------------------
// Edge-to-node attention. Block = (head-pair, n-tile 16, m-chunk 256),
// covers all 3 attrs x 2 heads. Stages fe/ae for its chunk in LDS (computed
// from E, swizzled), a_self inline via wvec. exp2-based. Partials to `part`.
template <int KE, bool L1>
__global__ void __launch_bounds__(256)
k_ea(const float* __restrict__ E,      // [3][N][N]
     const float* __restrict__ xsrc,   // X (stride 0) | xh [3][N][128]
     int xStride,
     const float* __restrict__ Wn,     // [3][8][F][KW]
     const float* __restrict__ aes,    // [8][KW]
     const float* __restrict__ We0,    // [8][3][4]
     const float* __restrict__ aen,    // [8][KE]
     const float* __restrict__ We1,    // [8][32][2] (L1 only)
     const float* __restrict__ adj,    // [N][M]
     float* __restrict__ part) {       // [3][8][N][MSL][8]
    constexpr int KW = L1 ? 8 : 16;
    __shared__ __align__(16) float sFe[HG * CH * KE];
    __shared__ __align__(16) float sAe[HG * CH];
    __shared__ __align__(16) float sWv[NATTR * HG * 128];
    __shared__ __align__(16) float sWc[HG * 3 * 2];

    int b = blockIdx.x;
    int ms = b & (MSL - 1);
    int nt = (b >> 6) & 7;
    int h0 = (b >> 9) * HG;
    int tid = threadIdx.x;
    int r = tid >> 4, l = tid & 15;
    int n = nt * 16 + r;
    int m0 = ms * CH;

    // ---- stage wvec[c][f] = log2e * sum_k Wn[a][h][f][k]*aes[h][k] ----
    for (int idx = tid; idx < NATTR * HG * 128; idx += 256) {
        int c = idx >> 7, f = idx & 127;
        int a = c / HG, h = h0 + (c % HG);
        const float* wp = Wn + ((size_t)(a * H + h) * F + f) * KW;
        const float* ap = aes + h * KW;
        float acc = 0.f;
#pragma unroll
        for (int k = 0; k < KW; ++k) acc += wp[k] * ap[k];
        sWv[idx] = acc * LOG2E;
    }
    if (L1) {
        if (tid < HG * 6) {
            int hh = tid / 6, rem = tid % 6, at = rem >> 1, k2 = rem & 1;
            int h = h0 + hh;
            float acc = 0.f;
            for (int c = 0; c < 32; ++c)
                acc += We0[((c >> 2) * 3 + at) * 4 + (c & 3)] *
                       We1[(h * 32 + c) * 2 + k2];
            sWc[(hh * 3 + at) * 2 + k2] = acc;
        }
        __syncthreads();
    }
    // ---- stage fe/ae: one m per thread, all HG heads (E read once) ----
    for (int mm = tid; mm < CH; mm += 256) {
        int m = m0 + mm;
        float e0 = E[m], e1 = E[M + m], e2 = E[2 * M + m];
#pragma unroll
        for (int hh = 0; hh < HG; ++hh) {
            int h = h0 + hh;
            if (!L1) {
                float4 v;
                float aa = 0.f;
#pragma unroll
                for (int k = 0; k < 4; ++k) {
                    float f = e0 * We0[(h * 3 + 0) * 4 + k] +
                              e1 * We0[(h * 3 + 1) * 4 + k] +
                              e2 * We0[(h * 3 + 2) * 4 + k];
                    (&v.x)[k] = f;
                    aa += f * aen[h * 4 + k];
                }
                *(float4*)&sFe[(hh * CH + swz4(mm)) * 4] = v;
                sAe[hh * CH + mm] = aa * LOG2E;
            } else {
                float f0 = e0 * sWc[(hh * 3 + 0) * 2 + 0] + e1 * sWc[(hh * 3 + 1) * 2 + 0] +
                           e2 * sWc[(hh * 3 + 2) * 2 + 0];
                float f1 = e0 * sWc[(hh * 3 + 0) * 2 + 1] + e1 * sWc[(hh * 3 + 1) * 2 + 1] +
                           e2 * sWc[(hh * 3 + 2) * 2 + 1];
                *(float2*)&sFe[(hh * CH + swz2(mm)) * 2] = make_float2(f0, f1);
                sAe[hh * CH + mm] = (f0 * aen[h * 2 + 0] + f1 * aen[h * 2 + 1]) * LOG2E;
            }
        }
    }
    __syncthreads();

    // ---- a_self inline: lane-coop dot of x-row with sWv ----
    float as[NATTR][HG];
#pragma unroll
    for (int a = 0; a < NATTR; ++a) {
        const float* xr = xsrc + (size_t)a * xStride + (size_t)n * F;
        float xv[8];
#pragma unroll
        for (int j = 0; j < 8; ++j) xv[j] = xr[l + 16 * j];
#pragma unroll
        for (int hh = 0; hh < HG; ++hh) {
            const float* wr = sWv + (a * HG + hh) * 128;
            float d = 0.f;
#pragma unroll
            for (int j = 0; j < 8; ++j) d += xv[j] * wr[l + 16 * j];
#pragma unroll
            for (int off = 1; off < 16; off <<= 1) d += __shfl_xor(d, off);
            as[a][hh] = d;
        }
    }

    // ---- main loop over the 256-m chunk ----
    float sum[HG][NATTR];
    float acc[HG][NATTR][KE];
#pragma unroll
    for (int hh = 0; hh < HG; ++hh)
#pragma unroll
        for (int a = 0; a < NATTR; ++a) {
            sum[hh][a] = 0.f;
#pragma unroll
            for (int k = 0; k < KE; ++k) acc[hh][a][k] = 0.f;
        }

    const float* adjp = adj + (size_t)n * M + m0;
    for (int i = l * 4; i < CH; i += 64) {
        const float4 av = *(const float4*)(adjp + i);
        float4 ev[HG];
#pragma unroll
        for (int hh = 0; hh < HG; ++hh)
            ev[hh] = *(const float4*)&sAe[hh * CH + i];
#pragma unroll
        for (int j = 0; j < 4; ++j) {
            float adjv = (&av.x)[j] * LOG2E;
#pragma unroll
            for (int hh = 0; hh < HG; ++hh) {
                float aev = (&ev[hh].x)[j];
                float fv[KE];
                if (KE == 4) {
                    const float4 fq = *(const float4*)&sFe[(hh * CH + swz4(i + j)) * 4];
                    fv[0] = fq.x; fv[1] = fq.y; fv[2] = fq.z; fv[3] = fq.w;
                } else {
                    const float2 fq = *(const float2*)&sFe[(hh * CH + swz2(i + j)) * 2];
                    fv[0] = fq.x; fv[1] = fq.y;
                }
#pragma unroll
                for (int a = 0; a < NATTR; ++a) {
                    float t = as[a][hh] + aev;
                    float p = __builtin_amdgcn_exp2f(fmaxf(t, 0.2f * t) + adjv);
                    sum[hh][a] += p;
#pragma unroll
                    for (int k = 0; k < KE; ++k) acc[hh][a][k] += p * fv[k];
                }
            }
        }
    }

    // ---- butterfly-reduce within each 16-lane row group, write partials ----
#pragma unroll
    for (int off = 1; off < 16; off <<= 1) {
#pragma unroll
        for (int hh = 0; hh < HG; ++hh)
#pragma unroll
            for (int a = 0; a < NATTR; ++a) {
                sum[hh][a] += __shfl_xor(sum[hh][a], off);
#pragma unroll
                for (int k = 0; k < KE; ++k) acc[hh][a][k] += __shfl_xor(acc[hh][a][k], off);
            }
    }
    if (l == 0) {
#pragma unroll
        for (int hh = 0; hh < HG; ++hh)
#pragma unroll
            for (int a = 0; a < NATTR; ++a) {
                float* pp = part + (((size_t)(a * H + h0 + hh) * N + n) * MSL + ms) * 8;
#pragma unroll
                for (int k = 0; k < KE; ++k) pp[k] = acc[hh][a][k];
                pp[7] = sum[hh][a];
            }
    }
}

// ---------------------------------------------------------------------------
// Mid: block = (a, h, ntile of 32 rows) = 96 blocks. Reduces part ONCE,
// inline feat for its 32 rows, feat2 = [feat|nf_e]@Wct + bct, s2/n2.
template <int K, int KE, bool FIRST>
__global__ void __launch_bounds__(256)
k_mid(const float* __restrict__ xsrc,    // X (stride 0) | xh
      int xStride,
      const float* __restrict__ Wn,      // [3][8][F][K]
      const float* __restrict__ part,    // [3][8][N][MSL][8]
      const float* __restrict__ be,      // [8][KE]
      const float* __restrict__ Wct,     // [8][K+KE][K]
      const float* __restrict__ bct,     // [8][K]
      const float* __restrict__ ans,     // [3][8][K]
      const float* __restrict__ ann,     // [3][8][K]
      const float* __restrict__ X,       // FIRST copy src
      float* __restrict__ out,
      float* __restrict__ feat2,         // [3][8][N][16]
      float* __restrict__ s2,            // [3][8][N]
      float* __restrict__ n2) {          // [3][8][N]
    constexpr int CIN = K + KE;
    __shared__ __align__(16) float sWn[F * K];
    __shared__ __align__(16) float sW[CIN * K];
    __shared__ __align__(16) float sIn[32 * CIN];
    __shared__ __align__(16) float sF2[32 * K];

    int b = blockIdx.x;
    int nt = b & 3, h = (b >> 2) & 7, a = b >> 5;
    int n0 = nt * 32;
    int tid = threadIdx.x;

    for (int i = tid; i < F * K; i += 256)
        sWn[i] = Wn[(size_t)(a * H + h) * F * K + i];
    for (int i = tid; i < CIN * K; i += 256) sW[i] = Wct[h * CIN * K + i];

    // ---- part reduce: 32 rows x 8 groups ----
    {
        int r = tid >> 3, g = tid & 7;
        int n = n0 + r;
        const float* pp = part + ((size_t)(a * H + h) * N + n) * MSL * 8;
        float av[4] = {0.f, 0.f, 0.f, 0.f};
        float sv = 0.f;
        for (int ms = g; ms < MSL; ms += 8) {
            const float4 x = *(const float4*)(pp + ms * 8);
            const float4 y = *(const float4*)(pp + ms * 8 + 4);
            av[0] += x.x; av[1] += x.y;
            if (KE == 4) { av[2] += x.z; av[3] += x.w; }
            sv += y.w;
        }
#pragma unroll
        for (int off = 1; off < 8; off <<= 1) {
#pragma unroll
            for (int k = 0; k < KE; ++k) av[k] += __shfl_xor(av[k], off);
            sv += __shfl_xor(sv, off);
        }
        if (g == 0) {
            float inv = 1.f / sv;
#pragma unroll
            for (int k = 0; k < KE; ++k)
                sIn[r * CIN + K + k] = av[k] * inv + be[h * KE + k];
        }
    }
    if (FIRST && h == 0) {
        for (int i = tid; i < 32 * F; i += 256) {
            int n = n0 + (i >> 7);
            int f = i & (F - 1);
            out[(n * NATTR + a) * OUTW + f] = X[n * F + f];
        }
    }
    __syncthreads();

    // ---- inline feat for the 32 rows ----
    for (int o = tid; o < 32 * K; o += 256) {
        int r = o / K, k = o % K;
        const float* xr = xsrc + (size_t)a * xStride + (size_t)(n0 + r) * F;
        float acc = 0.f;
        for (int f = 0; f < F; ++f) acc += xr[f] * sWn[f * K + k];
        sIn[r * CIN + k] = acc;
    }
    __syncthreads();

    // ---- feat2 + s2/n2 ----
    for (int o = tid; o < 32 * K; o += 256) {
        int r = o / K, k = o % K;
        float acc = bct[h * K + k];
        for (int c = 0; c < CIN; ++c) acc += sIn[r * CIN + c] * sW[c * K + k];
        sF2[o] = acc;
        feat2[((size_t)(a * H + h) * N + n0 + r) * 16 + k] = acc;
    }
    __syncthreads();
    if (tid < 32) {
        int r = tid;
        float ss = 0.f, nn = 0.f;
        for (int k = 0; k < K; ++k) {
            ss += sF2[r * K + k] * ans[(a * H + h) * K + k];
            nn += sF2[r * K + k] * ann[(a * H + h) * K + k];
        }
        s2[(a * H + h) * N + n0 + r] = ss;
        n2[(a * H + h) * N + n0 + r] = nn;
    }
}

// ---------------------------------------------------------------------------
// Node: block = (a, h, itile of 16 rows) = 192 blocks.
template <int K, bool FIRST>
__global__ void __launch_bounds__(256)
k_node(const float* __restrict__ feat2,   // [3][8][N][16]
       const float* __restrict__ s2,      // [3][8][N]
       const float* __restrict__ n2,      // [3][8][N]
       const float* __restrict__ Einfo,   // [3][N][N]
       const float* __restrict__ Amat,    // [3][N][N]
       const float* __restrict__ bn,      // [3][8][K]
       float* __restrict__ out, int outOff,
       float* __restrict__ xh_out,        // [3][N][128] or nullptr
       float* __restrict__ einfo_out) {   // [3][N][N] or nullptr
    __shared__ __align__(16) float sF2[N * K];
    __shared__ __align__(16) float sS2[N];
    __shared__ __align__(16) float sn2[N];
    __shared__ __align__(16) float sdE[N];
    __shared__ __align__(16) float scE[N];
    __shared__ __align__(16) float sAlpha[4 * N];
    __shared__ __align__(16) float sRed[256];

    int b = blockIdx.x;
    int itile = b & 7, h = (b >> 3) & 7, a = b >> 6;
    int tid = threadIdx.x;

    for (int i = tid; i < N * K; i += 256)
        sF2[i] = feat2[((size_t)(a * H + h) * N + i / K) * 16 + i % K];
    if (tid < N) {
        sS2[tid] = s2[(a * H + h) * N + tid];
        sn2[tid] = n2[(a * H + h) * N + tid];
    }
    __syncthreads();

    {
        int m = tid & 127, w = tid >> 7;
        const float* Ep = Einfo + (size_t)a * M;
        float dacc = 0.f, cacc = 0.f;
        for (int j = w * 64; j < w * 64 + 64; ++j) {
            float v = Ep[j * N + m];
            dacc += sn2[j] * v;
            cacc += v;
        }
        sRed[tid] = dacc;
        sAlpha[w * N + m] = cacc;
        __syncthreads();
        if (tid < N) {
            sdE[tid] = sRed[tid] + sRed[128 + tid];
            scE[tid] = sAlpha[tid] + sAlpha[N + tid];
        }
    }
    __syncthreads();

    for (int pass = 0; pass < 4; ++pass) {
        int r = tid >> 6;
        int lane = tid & 63;
        int i = itile * 16 + pass * 4 + r;
        float s = sS2[i];
        const float* Ap = Amat + ((size_t)a * N + i) * N;
        float v0 = leaky(s * scE[lane] + sdE[lane]) + Ap[lane];
        float v1 = leaky(s * scE[lane + 64] + sdE[lane + 64]) + Ap[lane + 64];
        float p0 = __expf(v0), p1 = __expf(v1);
        float ssum = p0 + p1;
#pragma unroll
        for (int off = 1; off < 64; off <<= 1) ssum += __shfl_xor(ssum, off);
        float inv = 1.f / ssum;
        float a0 = p0 * inv, a1 = p1 * inv;
        sAlpha[r * N + lane] = a0;
        sAlpha[r * N + lane + 64] = a1;
        if (FIRST && h == H - 1) {
            einfo_out[((size_t)a * N + i) * N + lane] = a0;
            einfo_out[((size_t)a * N + i) * N + lane + 64] = a1;
        }
        __syncthreads();
        {
            int rr = tid >> 6, g = (tid >> 4) & 3, k = tid & 15;
            float acc = 0.f;
            if (k < K) {
                for (int it = 0; it < 32; ++it) {
                    int mm = g + 4 * it;
                    acc += sAlpha[rr * N + mm] * sF2[mm * K + k];
                }
            }
            sRed[tid] = acc;
        }
        __syncthreads();
        {
            int rr = tid >> 6, k = tid & 63;
            if (k < K) {
                float tot = bn[(a * H + h) * K + k];
#pragma unroll
                for (int g = 0; g < 4; ++g) tot += sRed[rr * 64 + g * 16 + k];
                float e = tot > 0.f ? tot : __expf(tot) - 1.f;   // elu
                int i2 = itile * 16 + pass * 4 + rr;
                out[(i2 * NATTR + a) * OUTW + outOff + h * K + k] = e;
                if (FIRST)
                    xh_out[((size_t)a * N + i2) * F + h * K + k] = e;
            }
        }
        __syncthreads();
    }
}

// ---------------------------------------------------------------------------
extern "C" void kernel_launch(void* const* d_in, const int* in_sizes, int n_in,
                              void* d_out, int out_size, void* d_ws, size_t ws_size,
                              hipStream_t stream) {
    const float* X    = (const float*)d_in[0];
    const float* A    = (const float*)d_in[1];
    const float* E    = (const float*)d_in[2];
    const float* adj  = (const float*)d_in[3];
    const float* Wn0  = (const float*)d_in[4];
    const float* bn0  = (const float*)d_in[5];
    const float* an0s = (const float*)d_in[6];
    const float* an0n = (const float*)d_in[7];
    const float* Wn1  = (const float*)d_in[8];
    const float* bn1  = (const float*)d_in[9];
    const float* an1s = (const float*)d_in[10];
    const float* an1n = (const float*)d_in[11];
    const float* We0  = (const float*)d_in[12];
    const float* be0  = (const float*)d_in[13];
    const float* We1  = (const float*)d_in[14];
    const float* be1  = (const float*)d_in[15];
    const float* Wct0 = (const float*)d_in[16];
    const float* bct0 = (const float*)d_in[17];
    const float* Wct1 = (const float*)d_in[18];
    const float* bct1 = (const float*)d_in[19];
    const float* ae0s = (const float*)d_in[20];
    const float* ae0n = (const float*)d_in[21];
    const float* ae1s = (const float*)d_in[22];
    const float* ae1n = (const float*)d_in[23];
    float* out = (float*)d_out;

    float* p = (float*)d_ws;
    float* part  = p; p += (size_t)NATTR * H * N * MSL * 8;
    float* feat2 = p; p += NATTR * H * N * 16;
    float* s2b   = p; p += NATTR * H * N;
    float* n2b   = p; p += NATTR * H * N;
    float* einfo = p; p += NATTR * N * N;
    float* xh    = p; p += NATTR * N * F;

    // ---- layer 0 ----
    k_ea<4, false><<<dim3((H / HG) * 8 * MSL), dim3(256), 0, stream>>>(
        E, X, 0, Wn0, ae0s, We0, ae0n, nullptr, adj, part);
    k_mid<16, 4, true><<<dim3(96), dim3(256), 0, stream>>>(
        X, 0, Wn0, part, be0, Wct0, bct0, an0s, an0n, X, out,
        feat2, s2b, n2b);
    k_node<16, true><<<dim3(192), dim3(256), 0, stream>>>(
        feat2, s2b, n2b, E, A, bn0, out, F, xh, einfo);

    // ---- layer 1 ----
    k_ea<2, true><<<dim3((H / HG) * 8 * MSL), dim3(256), 0, stream>>>(
        E, xh, N * F, Wn1, ae1s, We0, ae1n, We1, adj, part);
    k_mid<8, 2, false><<<dim3(96), dim3(256), 0, stream>>>(
        xh, N * F, Wn1, part, be1, Wct1, bct1, an1s, an1n, nullptr, nullptr,
        feat2, s2b, n2b);
    k_node<8, false><<<dim3(192), dim3(256), 0, stream>>>(
        feat2, s2b, n2b, einfo, A, bn1, out, F + 128, nullptr, nullptr);
}